// Round 15
// baseline (75.266 us; speedup 1.0000x reference)
//
#include <hip/hip_runtime.h>

#define T_LEN 512
#define LOG2E 1.4426950408889634f

typedef float f32x2 __attribute__((ext_vector_type(2)));

__device__ __forceinline__ float rl(float v, int lane) {
    return __int_as_float(__builtin_amdgcn_readlane(__float_as_int(v), lane));
}
template<int CTRL>
__device__ __forceinline__ float qperm(float v) {
    return __int_as_float(__builtin_amdgcn_mov_dpp(__float_as_int(v), CTRL, 0xF, 0xF, true));
}

// v14: R6/R9 body (1 batch/wave, 64-lane: lane l -> gate l&3, k=l>>2,
// row=(l&3)*16+k; DPP-fused gate gathers; single LDS round trip per step)
// + R13's x-in-registers (v[8:15], 2 uniform ds_read_b128 per 8 steps,
// refilled in trans shadows) + 2 waves/SIMD with FORCED anti-phase:
// 512-thread blocks (8 waves; waves w and w+4 share a SIMD, same block)
// and waves 4-7 s_sleep(2) (~128 cyc = half period) before the loop, so one
// wave's ds_write->4x ds_read round trip hides under the partner's compute.
// Per-wave LDS region: [h 64][x 512][pad 16] = 592 floats.
__global__ __launch_bounds__(512, 1) void bilstm_head_kernel(
    const float* __restrict__ x,
    const float* __restrict__ W_ih_f, const float* __restrict__ W_hh_f,
    const float* __restrict__ b_ih_f, const float* __restrict__ b_hh_f,
    const float* __restrict__ W_ih_r, const float* __restrict__ W_hh_r,
    const float* __restrict__ b_ih_r, const float* __restrict__ b_hh_r,
    const float* __restrict__ W1, const float* __restrict__ b1,
    const float* __restrict__ W2, const float* __restrict__ b2,
    float* __restrict__ out)
{
    extern __shared__ float smem[];          // 8 waves * 592 floats

    const int tid  = threadIdx.x;
    const int wid  = tid >> 6;               // 0..7
    const int lane = tid & 63;
    const int b    = blockIdx.x * 8 + wid;

    const int gate = lane & 3;
    const int k    = lane >> 2;
    const int row  = gate * 16 + k;

    const bool  isg = (gate == 2);
    const float c1  = isg ? (-2.0f * LOG2E) : (-LOG2E);
    const float cm  = isg ? 2.0f : 1.0f;
    const float ca  = isg ? -1.0f : 0.0f;
    const float k2  = -2.0f * LOG2E;

    // weights prescaled by c1 so the matvec result feeds v_exp directly
    const float wih_p  = W_ih_f[row] * c1;
    const float bias_p = (b_ih_f[row] + b_hh_f[row]) * c1;
    f32x2 wp[8];
#pragma unroll
    for (int n = 0; n < 8; ++n) {
        wp[n].x = W_hh_f[row * 16 + 2 * n]     * c1;
        wp[n].y = W_hh_f[row * 16 + 2 * n + 1] * c1;
    }

    const int wfl = wid * 592;               // wave base (floats)
    // stage this batch's x row (coalesced, wave-private region)
#pragma unroll
    for (int i = 0; i < 8; ++i)
        smem[wfl + 64 + i * 64 + lane] = x[b * T_LEN + i * 64 + lane];

    const unsigned vB = (unsigned)(wfl * 4);             // h read base (bytes)
    const unsigned vW = vB + (unsigned)(row * 4);        // h write addr
    unsigned vX = (unsigned)((wfl + 64) * 4);            // x base (bytes)
    float c = 0.0f;

    // anti-phase: the SIMD-partner wave (wid^4, same block) starts ~128 cyc
    // (~half the step period) later so the LDS round trips interleave.
    if (wid & 4) __builtin_amdgcn_s_sleep(2);

// One LSTM step. XC = x register (v8..v15). FILL fills the trans shadow
// (s_nop, or the x refill ds_read in steps 3/7 -- issued BEFORE the tail DS
// so the head waits (3)(2)(1)(0) stay uniform across both step kinds).
#define LSTM_STEP(XC, FILL) \
    "v_fma_f32 v20, " XC ", %[wih], %[bias]\n\t" \
    "v_mov_b32 v21, 0\n\t" \
    "s_waitcnt lgkmcnt(3)\n\t" \
    "v_pk_fma_f32 v[20:21], v[32:33], %[w01], v[20:21]\n\t" \
    "v_pk_fma_f32 v[20:21], v[34:35], %[w23], v[20:21]\n\t" \
    "s_waitcnt lgkmcnt(2)\n\t" \
    "v_pk_mul_f32 v[24:25], v[36:37], %[w45]\n\t" \
    "v_pk_fma_f32 v[24:25], v[38:39], %[w67], v[24:25]\n\t" \
    "s_waitcnt lgkmcnt(1)\n\t" \
    "v_pk_fma_f32 v[20:21], v[40:41], %[w89], v[20:21]\n\t" \
    "v_pk_fma_f32 v[24:25], v[42:43], %[wAB], v[24:25]\n\t" \
    "s_waitcnt lgkmcnt(0)\n\t" \
    "v_pk_fma_f32 v[20:21], v[44:45], %[wCD], v[20:21]\n\t" \
    "v_pk_fma_f32 v[24:25], v[46:47], %[wEF], v[24:25]\n\t" \
    "v_pk_add_f32 v[20:21], v[20:21], v[24:25]\n\t" \
    "v_add_f32 v20, v20, v21\n\t" \
    "v_exp_f32 v22, v20\n\t" \
    FILL \
    "s_nop 0\n\t" \
    "v_add_f32 v22, 1.0, v22\n\t" \
    "v_rcp_f32 v22, v22\n\t" \
    "s_nop 1\n\t" \
    "v_fma_f32 v23, v22, %[cm], %[ca]\n\t" \
    "s_nop 1\n\t" \
    "v_mov_b32_dpp v26, v23 quad_perm:[1,0,3,2] row_mask:0xf bank_mask:0xf\n\t" \
    "v_mul_f32_dpp v22, v23, v23 quad_perm:[2,3,0,1] row_mask:0xf bank_mask:0xf\n\t" \
    "s_nop 0\n\t" \
    "v_fma_f32 %[c], v26, %[c], v22\n\t" \
    "v_mul_f32 v22, %[k2], %[c]\n\t" \
    "v_exp_f32 v22, v22\n\t" \
    "s_nop 1\n\t" \
    "v_add_f32 v22, 1.0, v22\n\t" \
    "v_rcp_f32 v22, v22\n\t" \
    "s_nop 1\n\t" \
    "v_fma_f32 v22, v22, 2.0, -1.0\n\t" \
    "v_mul_f32_dpp v29, v23, v22 quad_perm:[3,2,1,0] row_mask:0xf bank_mask:0xf\n\t" \
    "s_nop 0\n\t" \
    "ds_write_b32 %[vW], v29\n\t" \
    "ds_read_b128 v[32:35], %[vB] offset:0\n\t" \
    "ds_read_b128 v[36:39], %[vB] offset:16\n\t" \
    "ds_read_b128 v[40:43], %[vB] offset:32\n\t" \
    "ds_read_b128 v[44:47], %[vB] offset:48\n\t"

#define NOFILL "s_nop 0\n\t"
#define FILLA  "ds_read_b128 v[8:11], %[vX] offset:32\n\t"
#define FILLB  "ds_read_b128 v[12:15], %[vX] offset:48\n\t"

    asm volatile(
        "s_waitcnt lgkmcnt(0)\n\t"           // x staging drained
        "v_mov_b32 v29, 0\n\t"
        "ds_read_b128 v[8:11],  %[vX] offset:0\n\t"   // x0..x3
        "ds_read_b128 v[12:15], %[vX] offset:16\n\t"  // x4..x7
        "ds_write_b32 %[vW], v29\n\t"                 // h=0 publish
        "ds_read_b128 v[32:35], %[vB] offset:0\n\t"
        "ds_read_b128 v[36:39], %[vB] offset:16\n\t"
        "ds_read_b128 v[40:43], %[vB] offset:32\n\t"
        "ds_read_b128 v[44:47], %[vB] offset:48\n\t"
        "s_waitcnt lgkmcnt(4)\n\t"           // x reads + write retired
        "s_mov_b32 s20, 0\n\t"
        "1:\n\t"
        LSTM_STEP("v8",  NOFILL)
        LSTM_STEP("v9",  NOFILL)
        LSTM_STEP("v10", NOFILL)
        LSTM_STEP("v11", FILLA)
        LSTM_STEP("v12", NOFILL)
        LSTM_STEP("v13", NOFILL)
        LSTM_STEP("v14", NOFILL)
        LSTM_STEP("v15", FILLB)
        "v_add_u32 %[vX], 32, %[vX]\n\t"
        "s_add_u32 s20, s20, 1\n\t"
        "s_cmp_lt_u32 s20, 64\n\t"
        "s_cbranch_scc1 1b\n\t"
        "s_waitcnt lgkmcnt(0)\n\t"           // final h write drained
        : [c]"+v"(c), [vX]"+v"(vX)
        : [vB]"v"(vB), [vW]"v"(vW),
          [wih]"v"(wih_p), [bias]"v"(bias_p),
          [cm]"v"(cm), [ca]"v"(ca), [k2]"v"(k2),
          [w01]"v"(wp[0]), [w23]"v"(wp[1]), [w45]"v"(wp[2]), [w67]"v"(wp[3]),
          [w89]"v"(wp[4]), [wAB]"v"(wp[5]), [wCD]"v"(wp[6]), [wEF]"v"(wp[7])
        : "v8","v9","v10","v11","v12","v13","v14","v15",
          "v20","v21","v22","v23","v24","v25","v26","v27","v28","v29",
          "v32","v33","v34","v35","v36","v37","v38","v39",
          "v40","v41","v42","v43","v44","v45","v46","v47",
          "s20","scc","memory");
#undef LSTM_STEP
#undef NOFILL
#undef FILLA
#undef FILLB

    // final forward hidden state sits in LDS gate-0 region (rows 0..15)
    float hs[16];
#pragma unroll
    for (int n = 0; n < 16; ++n) hs[n] = smem[wfl + n];

    // ---- reverse direction: single LSTM step on x[:, T-1] from zero state ----
    const float wihr  = W_ih_r[row];
    const float biasr = b_ih_r[row] + b_hh_r[row];
    const float xlast = smem[wfl + 64 + 511];

    const float zr   = fmaf(xlast, wihr, biasr);
    const float er   = __builtin_amdgcn_exp2f(zr * c1);
    const float rr_  = __builtin_amdgcn_rcpf(1.0f + er);
    const float actr = fmaf(rr_, cm, ca);
    const float gr   = qperm<0x4E>(actr);
    const float or_  = qperm<0x1B>(actr);
    const float cr   = actr * gr;                      // sig(i)*tanh(g), c0 = 0
    const float e2r  = __builtin_amdgcn_exp2f(cr * (-2.0f * LOG2E));
    const float thr_ = fmaf(__builtin_amdgcn_rcpf(1.0f + e2r), 2.0f, -1.0f);
    const float hbw  = or_ * thr_;

    float hr[16];
#pragma unroll
    for (int n = 0; n < 16; ++n) hr[n] = rl(hbw, 4 * n);

    // ---- MLP head: hid = LeakyReLU([h_fwd, h_bwd] @ W1.T + b1); out = hid @ W2.T + b2
    const int m = lane & 15;
    float hid = b1[m];
#pragma unroll
    for (int n = 0; n < 16; ++n) hid = fmaf(hs[n], W1[m * 32 + n], hid);
#pragma unroll
    for (int n = 0; n < 16; ++n) hid = fmaf(hr[n], W1[m * 32 + 16 + n], hid);
    hid = (hid > 0.0f) ? hid : (0.2f * hid);

    float v = hid * W2[m];
    v += __shfl_xor(v, 1);
    v += __shfl_xor(v, 2);
    v += __shfl_xor(v, 4);
    v += __shfl_xor(v, 8);
    if (lane == 0) out[b] = v + b2[0];
}

extern "C" void kernel_launch(void* const* d_in, const int* in_sizes, int n_in,
                              void* d_out, int out_size, void* d_ws, size_t ws_size,
                              hipStream_t stream) {
    const float* x      = (const float*)d_in[0];
    const float* W_ih_f = (const float*)d_in[1];
    const float* W_hh_f = (const float*)d_in[2];
    const float* b_ih_f = (const float*)d_in[3];
    const float* b_hh_f = (const float*)d_in[4];
    const float* W_ih_r = (const float*)d_in[5];
    const float* W_hh_r = (const float*)d_in[6];
    const float* b_ih_r = (const float*)d_in[7];
    const float* b_hh_r = (const float*)d_in[8];
    const float* W1     = (const float*)d_in[9];
    const float* b1     = (const float*)d_in[10];
    const float* W2     = (const float*)d_in[11];
    const float* b2     = (const float*)d_in[12];
    float* out = (float*)d_out;

    const int B = in_sizes[0] / T_LEN;   // 2048
    dim3 grid(B / 8), block(512);        // 8 waves/block -> 2 waves/SIMD, same block
    size_t lds_bytes = 8 * 592 * sizeof(float);   // 18944 B/block
    hipLaunchKernelGGL(bilstm_head_kernel, grid, block, lds_bytes, stream,
                       x, W_ih_f, W_hh_f, b_ih_f, b_hh_f,
                       W_ih_r, W_hh_r, b_ih_r, b_hh_r,
                       W1, b1, W2, b2, out);
}

// Round 16
// 75.252 us; speedup vs baseline: 1.0002x; 1.0002x over previous
//
#include <hip/hip_runtime.h>

#define T_LEN 512
#define LOG2E 1.4426950408889634f

typedef float f32x2 __attribute__((ext_vector_type(2)));

__device__ __forceinline__ float rl(float v, int lane) {
    return __int_as_float(__builtin_amdgcn_readlane(__float_as_int(v), lane));
}
template<int CTRL>
__device__ __forceinline__ float qperm(float v) {
    return __int_as_float(__builtin_amdgcn_mov_dpp(__float_as_int(v), CTRL, 0xF, 0xF, true));
}

// v15 = v14 + leader/follower wave priority. 8 waves/block (512 thr); waves
// w and w+4 share a SIMD. Waves 0-3 run s_setprio(1) (leader), waves 4-7
// stay prio 0 (follower) and sleep ~128cyc at loop entry. Leader's 118-cyc
// issue block is never stretched by round-robin; follower issues only inside
// leader's ~170-cyc LDS-RT stall -> stable anti-phase, period ~288 instead
// of the in-phase ~385 measured in v14. Body identical to v14 (R6 64-lane
// 1-batch layout, DPP-fused gathers, x in v[8:15], single LDS RT per step).
// Per-wave LDS region: [h 64][x 512][pad 16] = 592 floats.
__global__ __launch_bounds__(512, 1) void bilstm_head_kernel(
    const float* __restrict__ x,
    const float* __restrict__ W_ih_f, const float* __restrict__ W_hh_f,
    const float* __restrict__ b_ih_f, const float* __restrict__ b_hh_f,
    const float* __restrict__ W_ih_r, const float* __restrict__ W_hh_r,
    const float* __restrict__ b_ih_r, const float* __restrict__ b_hh_r,
    const float* __restrict__ W1, const float* __restrict__ b1,
    const float* __restrict__ W2, const float* __restrict__ b2,
    float* __restrict__ out)
{
    extern __shared__ float smem[];          // 8 waves * 592 floats

    const int tid  = threadIdx.x;
    const int wid  = tid >> 6;               // 0..7
    const int lane = tid & 63;
    const int b    = blockIdx.x * 8 + wid;

    const int gate = lane & 3;
    const int k    = lane >> 2;
    const int row  = gate * 16 + k;

    const bool  isg = (gate == 2);
    const float c1  = isg ? (-2.0f * LOG2E) : (-LOG2E);
    const float cm  = isg ? 2.0f : 1.0f;
    const float ca  = isg ? -1.0f : 0.0f;
    const float k2  = -2.0f * LOG2E;

    // weights prescaled by c1 so the matvec result feeds v_exp directly
    const float wih_p  = W_ih_f[row] * c1;
    const float bias_p = (b_ih_f[row] + b_hh_f[row]) * c1;
    f32x2 wp[8];
#pragma unroll
    for (int n = 0; n < 8; ++n) {
        wp[n].x = W_hh_f[row * 16 + 2 * n]     * c1;
        wp[n].y = W_hh_f[row * 16 + 2 * n + 1] * c1;
    }

    const int wfl = wid * 592;               // wave base (floats)
    // stage this batch's x row (coalesced, wave-private region)
#pragma unroll
    for (int i = 0; i < 8; ++i)
        smem[wfl + 64 + i * 64 + lane] = x[b * T_LEN + i * 64 + lane];

    const unsigned vB = (unsigned)(wfl * 4);             // h read base (bytes)
    const unsigned vW = vB + (unsigned)(row * 4);        // h write addr
    unsigned vX = (unsigned)((wfl + 64) * 4);            // x base (bytes)
    float c = 0.0f;

    // leader/follower: leader (wid<4) gets priority 1 -> its issue block is
    // never interleaved; follower fills the leader's LDS-RT stall window.
    if (wid < 4) {
        __builtin_amdgcn_s_setprio(1);
    } else {
        __builtin_amdgcn_s_sleep(2);         // ~128 cyc initial anti-phase
    }

// One LSTM step. XC = x register (v8..v15). FILL fills the trans shadow
// (s_nop, or the x refill ds_read in steps 3/7 -- issued BEFORE the tail DS
// so the head waits (3)(2)(1)(0) stay uniform across both step kinds).
#define LSTM_STEP(XC, FILL) \
    "v_fma_f32 v20, " XC ", %[wih], %[bias]\n\t" \
    "v_mov_b32 v21, 0\n\t" \
    "s_waitcnt lgkmcnt(3)\n\t" \
    "v_pk_fma_f32 v[20:21], v[32:33], %[w01], v[20:21]\n\t" \
    "v_pk_fma_f32 v[20:21], v[34:35], %[w23], v[20:21]\n\t" \
    "s_waitcnt lgkmcnt(2)\n\t" \
    "v_pk_mul_f32 v[24:25], v[36:37], %[w45]\n\t" \
    "v_pk_fma_f32 v[24:25], v[38:39], %[w67], v[24:25]\n\t" \
    "s_waitcnt lgkmcnt(1)\n\t" \
    "v_pk_fma_f32 v[20:21], v[40:41], %[w89], v[20:21]\n\t" \
    "v_pk_fma_f32 v[24:25], v[42:43], %[wAB], v[24:25]\n\t" \
    "s_waitcnt lgkmcnt(0)\n\t" \
    "v_pk_fma_f32 v[20:21], v[44:45], %[wCD], v[20:21]\n\t" \
    "v_pk_fma_f32 v[24:25], v[46:47], %[wEF], v[24:25]\n\t" \
    "v_pk_add_f32 v[20:21], v[20:21], v[24:25]\n\t" \
    "v_add_f32 v20, v20, v21\n\t" \
    "v_exp_f32 v22, v20\n\t" \
    FILL \
    "s_nop 0\n\t" \
    "v_add_f32 v22, 1.0, v22\n\t" \
    "v_rcp_f32 v22, v22\n\t" \
    "s_nop 1\n\t" \
    "v_fma_f32 v23, v22, %[cm], %[ca]\n\t" \
    "s_nop 1\n\t" \
    "v_mov_b32_dpp v26, v23 quad_perm:[1,0,3,2] row_mask:0xf bank_mask:0xf\n\t" \
    "v_mul_f32_dpp v22, v23, v23 quad_perm:[2,3,0,1] row_mask:0xf bank_mask:0xf\n\t" \
    "s_nop 0\n\t" \
    "v_fma_f32 %[c], v26, %[c], v22\n\t" \
    "v_mul_f32 v22, %[k2], %[c]\n\t" \
    "v_exp_f32 v22, v22\n\t" \
    "s_nop 1\n\t" \
    "v_add_f32 v22, 1.0, v22\n\t" \
    "v_rcp_f32 v22, v22\n\t" \
    "s_nop 1\n\t" \
    "v_fma_f32 v22, v22, 2.0, -1.0\n\t" \
    "v_mul_f32_dpp v29, v23, v22 quad_perm:[3,2,1,0] row_mask:0xf bank_mask:0xf\n\t" \
    "s_nop 0\n\t" \
    "ds_write_b32 %[vW], v29\n\t" \
    "ds_read_b128 v[32:35], %[vB] offset:0\n\t" \
    "ds_read_b128 v[36:39], %[vB] offset:16\n\t" \
    "ds_read_b128 v[40:43], %[vB] offset:32\n\t" \
    "ds_read_b128 v[44:47], %[vB] offset:48\n\t"

#define NOFILL "s_nop 0\n\t"
#define FILLA  "ds_read_b128 v[8:11], %[vX] offset:32\n\t"
#define FILLB  "ds_read_b128 v[12:15], %[vX] offset:48\n\t"

    asm volatile(
        "s_waitcnt lgkmcnt(0)\n\t"           // x staging drained
        "v_mov_b32 v29, 0\n\t"
        "ds_read_b128 v[8:11],  %[vX] offset:0\n\t"   // x0..x3
        "ds_read_b128 v[12:15], %[vX] offset:16\n\t"  // x4..x7
        "ds_write_b32 %[vW], v29\n\t"                 // h=0 publish
        "ds_read_b128 v[32:35], %[vB] offset:0\n\t"
        "ds_read_b128 v[36:39], %[vB] offset:16\n\t"
        "ds_read_b128 v[40:43], %[vB] offset:32\n\t"
        "ds_read_b128 v[44:47], %[vB] offset:48\n\t"
        "s_waitcnt lgkmcnt(4)\n\t"           // x reads + write retired
        "s_mov_b32 s20, 0\n\t"
        "1:\n\t"
        LSTM_STEP("v8",  NOFILL)
        LSTM_STEP("v9",  NOFILL)
        LSTM_STEP("v10", NOFILL)
        LSTM_STEP("v11", FILLA)
        LSTM_STEP("v12", NOFILL)
        LSTM_STEP("v13", NOFILL)
        LSTM_STEP("v14", NOFILL)
        LSTM_STEP("v15", FILLB)
        "v_add_u32 %[vX], 32, %[vX]\n\t"
        "s_add_u32 s20, s20, 1\n\t"
        "s_cmp_lt_u32 s20, 64\n\t"
        "s_cbranch_scc1 1b\n\t"
        "s_waitcnt lgkmcnt(0)\n\t"           // final h write drained
        : [c]"+v"(c), [vX]"+v"(vX)
        : [vB]"v"(vB), [vW]"v"(vW),
          [wih]"v"(wih_p), [bias]"v"(bias_p),
          [cm]"v"(cm), [ca]"v"(ca), [k2]"v"(k2),
          [w01]"v"(wp[0]), [w23]"v"(wp[1]), [w45]"v"(wp[2]), [w67]"v"(wp[3]),
          [w89]"v"(wp[4]), [wAB]"v"(wp[5]), [wCD]"v"(wp[6]), [wEF]"v"(wp[7])
        : "v8","v9","v10","v11","v12","v13","v14","v15",
          "v20","v21","v22","v23","v24","v25","v26","v27","v28","v29",
          "v32","v33","v34","v35","v36","v37","v38","v39",
          "v40","v41","v42","v43","v44","v45","v46","v47",
          "s20","scc","memory");
#undef LSTM_STEP
#undef NOFILL
#undef FILLA
#undef FILLB

    // restore neutral priority for the epilogue
    __builtin_amdgcn_s_setprio(0);

    // final forward hidden state sits in LDS gate-0 region (rows 0..15)
    float hs[16];
#pragma unroll
    for (int n = 0; n < 16; ++n) hs[n] = smem[wfl + n];

    // ---- reverse direction: single LSTM step on x[:, T-1] from zero state ----
    const float wihr  = W_ih_r[row];
    const float biasr = b_ih_r[row] + b_hh_r[row];
    const float xlast = smem[wfl + 64 + 511];

    const float zr   = fmaf(xlast, wihr, biasr);
    const float er   = __builtin_amdgcn_exp2f(zr * c1);
    const float rr_  = __builtin_amdgcn_rcpf(1.0f + er);
    const float actr = fmaf(rr_, cm, ca);
    const float gr   = qperm<0x4E>(actr);
    const float or_  = qperm<0x1B>(actr);
    const float cr   = actr * gr;                      // sig(i)*tanh(g), c0 = 0
    const float e2r  = __builtin_amdgcn_exp2f(cr * (-2.0f * LOG2E));
    const float thr_ = fmaf(__builtin_amdgcn_rcpf(1.0f + e2r), 2.0f, -1.0f);
    const float hbw  = or_ * thr_;

    float hr[16];
#pragma unroll
    for (int n = 0; n < 16; ++n) hr[n] = rl(hbw, 4 * n);

    // ---- MLP head: hid = LeakyReLU([h_fwd, h_bwd] @ W1.T + b1); out = hid @ W2.T + b2
    const int m = lane & 15;
    float hid = b1[m];
#pragma unroll
    for (int n = 0; n < 16; ++n) hid = fmaf(hs[n], W1[m * 32 + n], hid);
#pragma unroll
    for (int n = 0; n < 16; ++n) hid = fmaf(hr[n], W1[m * 32 + 16 + n], hid);
    hid = (hid > 0.0f) ? hid : (0.2f * hid);

    float v = hid * W2[m];
    v += __shfl_xor(v, 1);
    v += __shfl_xor(v, 2);
    v += __shfl_xor(v, 4);
    v += __shfl_xor(v, 8);
    if (lane == 0) out[b] = v + b2[0];
}

extern "C" void kernel_launch(void* const* d_in, const int* in_sizes, int n_in,
                              void* d_out, int out_size, void* d_ws, size_t ws_size,
                              hipStream_t stream) {
    const float* x      = (const float*)d_in[0];
    const float* W_ih_f = (const float*)d_in[1];
    const float* W_hh_f = (const float*)d_in[2];
    const float* b_ih_f = (const float*)d_in[3];
    const float* b_hh_f = (const float*)d_in[4];
    const float* W_ih_r = (const float*)d_in[5];
    const float* W_hh_r = (const float*)d_in[6];
    const float* b_ih_r = (const float*)d_in[7];
    const float* b_hh_r = (const float*)d_in[8];
    const float* W1     = (const float*)d_in[9];
    const float* b1     = (const float*)d_in[10];
    const float* W2     = (const float*)d_in[11];
    const float* b2     = (const float*)d_in[12];
    float* out = (float*)d_out;

    const int B = in_sizes[0] / T_LEN;   // 2048
    dim3 grid(B / 8), block(512);        // 8 waves/block -> 2 waves/SIMD, same block
    size_t lds_bytes = 8 * 592 * sizeof(float);   // 18944 B/block
    hipLaunchKernelGGL(bilstm_head_kernel, grid, block, lds_bytes, stream,
                       x, W_ih_f, W_hh_f, b_ih_f, b_hh_f,
                       W_ih_r, W_hh_r, b_ih_r, b_hh_r,
                       W1, b1, W2, b2, out);
}

// Round 17
// 69.608 us; speedup vs baseline: 1.0813x; 1.0811x over previous
//
#include <hip/hip_runtime.h>

#define T_LEN 512
#define LOG2E 1.4426950408889634f

typedef float f32x2 __attribute__((ext_vector_type(2)));

// v16 = v13 verbatim (best measured: 69.9 us dur / 75.0 steady).
// 2 batches/wave (lanes 0-31 batch A, 32-63 batch B); hl=lane&31, k=hl>>1,
// p=hl&1; sub-row0 = {i,f}[k] (sigmoid), sub-row1 = {g,o}[k] (tanh/sigmoid).
// x[t..t+7] held in v[8:15] via 2 uniform ds_read_b128 per 8-step iteration
// (refilled in steps 3/7 trans shadows) -> step head z-fma needs NO wait and
// fills the first lgkm shadow. h broadcast: p0 lanes ds_write h[k], all
// lanes 4x uniform ds_read_b128; in-order queue [w,r1..r4(+refill)] ->
// staggered waits (3)(2)(1)(0). Structural floor: period 352 cyc/pair =
// LDS-RT(~170) + matvec issue (64, fp32-pipe-optimal) + act chain (~110);
// all alternative transports/packings measured worse (R8/R10/R11/R12/R14/R15).
// LDS per batch: [h 16][hbwd 16][x 512][pad 16] = 560 floats.
__global__ __launch_bounds__(256, 1) void bilstm_head_kernel(
    const float* __restrict__ x,
    const float* __restrict__ W_ih_f, const float* __restrict__ W_hh_f,
    const float* __restrict__ b_ih_f, const float* __restrict__ b_hh_f,
    const float* __restrict__ W_ih_r, const float* __restrict__ W_hh_r,
    const float* __restrict__ b_ih_r, const float* __restrict__ b_hh_r,
    const float* __restrict__ W1, const float* __restrict__ b1,
    const float* __restrict__ W2, const float* __restrict__ b2,
    float* __restrict__ out)
{
    extern __shared__ float smem[];          // 8 regions * 560 floats

    const int tid  = threadIdx.x;
    const int wid  = tid >> 6;
    const int lane = tid & 63;
    const int half = lane >> 5;
    const int hl   = lane & 31;
    const int b    = blockIdx.x * 8 + wid * 2 + half;

    const int k = hl >> 1;
    const int p = hl & 1;
    const int row0 = p * 16 + k;             // sigmoid row (i or f)
    const int row1 = (2 + p) * 16 + k;       // g (tanh) or o (sigmoid)

    const float c1_0 = -LOG2E;
    const float c1_1 = (p == 0) ? (-2.0f * LOG2E) : (-LOG2E);
    const float cm1  = (p == 0) ? 2.0f : 1.0f;
    const float ca1  = (p == 0) ? -1.0f : 0.0f;
    const float k2   = -2.0f * LOG2E;

    // prescaled weights: matvec result feeds v_exp directly
    const float wih0  = W_ih_f[row0] * c1_0;
    const float bias0 = (b_ih_f[row0] + b_hh_f[row0]) * c1_0;
    const float wih1  = W_ih_f[row1] * c1_1;
    const float bias1 = (b_ih_f[row1] + b_hh_f[row1]) * c1_1;
    f32x2 w0p[8], w1p[8];
#pragma unroll
    for (int n = 0; n < 8; ++n) {
        w0p[n].x = W_hh_f[row0 * 16 + 2 * n]     * c1_0;
        w0p[n].y = W_hh_f[row0 * 16 + 2 * n + 1] * c1_0;
        w1p[n].x = W_hh_f[row1 * 16 + 2 * n]     * c1_1;
        w1p[n].y = W_hh_f[row1 * 16 + 2 * n + 1] * c1_1;
    }

    const int rbase = (wid * 2 + half) * 560;        // region base (floats)
    // stage this batch's x row (32 lanes per batch)
#pragma unroll
    for (int i = 0; i < 16; ++i)
        smem[rbase + 32 + i * 32 + hl] = x[b * T_LEN + i * 32 + hl];

    const unsigned vB = (unsigned)(rbase * 4);               // h read base
    const unsigned vW = (unsigned)((rbase + p * 16 + k) * 4); // h write addr
    unsigned vX = (unsigned)((rbase + 32) * 4);              // x byte base
    float c = 0.0f;

// One LSTM step. XC = x register (v8..v15). FILL = trans-shadow filler
// (s_nop 0, or the x refill ds_read in steps 3/7).
#define LSTM_STEP(XC, FILL) \
    "v_fma_f32 v20, " XC ", %[wih0], %[bias0]\n\t" \
    "v_mov_b32 v21, 0\n\t" \
    "v_fma_f32 v22, " XC ", %[wih1], %[bias1]\n\t" \
    "v_mov_b32 v23, 0\n\t" \
    "s_waitcnt lgkmcnt(3)\n\t" \
    "v_pk_fma_f32 v[20:21], v[32:33], %[w00], v[20:21]\n\t" \
    "v_pk_fma_f32 v[22:23], v[32:33], %[w10], v[22:23]\n\t" \
    "v_pk_fma_f32 v[20:21], v[34:35], %[w01], v[20:21]\n\t" \
    "v_pk_fma_f32 v[22:23], v[34:35], %[w11], v[22:23]\n\t" \
    "s_waitcnt lgkmcnt(2)\n\t" \
    "v_pk_fma_f32 v[20:21], v[36:37], %[w02], v[20:21]\n\t" \
    "v_pk_fma_f32 v[22:23], v[36:37], %[w12], v[22:23]\n\t" \
    "v_pk_fma_f32 v[20:21], v[38:39], %[w03], v[20:21]\n\t" \
    "v_pk_fma_f32 v[22:23], v[38:39], %[w13], v[22:23]\n\t" \
    "s_waitcnt lgkmcnt(1)\n\t" \
    "v_pk_fma_f32 v[20:21], v[40:41], %[w04], v[20:21]\n\t" \
    "v_pk_fma_f32 v[22:23], v[40:41], %[w14], v[22:23]\n\t" \
    "v_pk_fma_f32 v[20:21], v[42:43], %[w05], v[20:21]\n\t" \
    "v_pk_fma_f32 v[22:23], v[42:43], %[w15], v[22:23]\n\t" \
    "s_waitcnt lgkmcnt(0)\n\t" \
    "v_pk_fma_f32 v[20:21], v[44:45], %[w06], v[20:21]\n\t" \
    "v_pk_fma_f32 v[22:23], v[44:45], %[w16], v[22:23]\n\t" \
    "v_pk_fma_f32 v[20:21], v[46:47], %[w07], v[20:21]\n\t" \
    "v_pk_fma_f32 v[22:23], v[46:47], %[w17], v[22:23]\n\t" \
    "v_add_f32 v20, v20, v21\n\t" \
    "v_add_f32 v22, v22, v23\n\t" \
    "v_exp_f32 v24, v20\n\t" \
    "v_exp_f32 v25, v22\n\t" \
    FILL \
    "v_add_f32 v24, 1.0, v24\n\t" \
    "v_add_f32 v25, 1.0, v25\n\t" \
    "v_rcp_f32 v24, v24\n\t" \
    "v_rcp_f32 v25, v25\n\t" \
    "s_nop 1\n\t" \
    "v_fma_f32 v25, v25, %[cm1], %[ca1]\n\t" \
    "v_mul_f32 v28, v24, v25\n\t" \
    "v_mov_b32_dpp v26, v24 quad_perm:[1,0,3,2] row_mask:0xf bank_mask:0xf\n\t" \
    "v_mov_b32_dpp v27, v25 quad_perm:[1,0,3,2] row_mask:0xf bank_mask:0xf\n\t" \
    "v_fma_f32 %[c], v26, %[c], v28\n\t" \
    "v_mul_f32 v28, %[k2], %[c]\n\t" \
    "v_exp_f32 v28, v28\n\t" \
    "s_nop 1\n\t" \
    "v_add_f32 v28, 1.0, v28\n\t" \
    "v_rcp_f32 v28, v28\n\t" \
    "s_nop 1\n\t" \
    "v_fma_f32 v28, v28, 2.0, -1.0\n\t" \
    "v_mul_f32 v29, v27, v28\n\t" \
    "ds_write_b32 %[vW], v29\n\t" \
    "ds_read_b128 v[32:35], %[vB] offset:0\n\t" \
    "ds_read_b128 v[36:39], %[vB] offset:16\n\t" \
    "ds_read_b128 v[40:43], %[vB] offset:32\n\t" \
    "ds_read_b128 v[44:47], %[vB] offset:48\n\t"

#define NOFILL "s_nop 0\n\t"
#define FILLA  "ds_read_b128 v[8:11], %[vX] offset:32\n\t"
#define FILLB  "ds_read_b128 v[12:15], %[vX] offset:48\n\t"

    asm volatile(
        "s_waitcnt lgkmcnt(0)\n\t"           // x staging drained
        "v_mov_b32 v29, 0\n\t"
        "ds_read_b128 v[8:11],  %[vX] offset:0\n\t"   // x0..x3
        "ds_read_b128 v[12:15], %[vX] offset:16\n\t"  // x4..x7
        "ds_write_b32 %[vW], v29\n\t"                 // h=0 publish
        "ds_read_b128 v[32:35], %[vB] offset:0\n\t"
        "ds_read_b128 v[36:39], %[vB] offset:16\n\t"
        "ds_read_b128 v[40:43], %[vB] offset:32\n\t"
        "ds_read_b128 v[44:47], %[vB] offset:48\n\t"
        "s_waitcnt lgkmcnt(4)\n\t"           // xA,xB,write retired
        "s_mov_b32 s20, 0\n\t"
        "1:\n\t"
        LSTM_STEP("v8",  NOFILL)
        LSTM_STEP("v9",  NOFILL)
        LSTM_STEP("v10", NOFILL)
        LSTM_STEP("v11", FILLA)
        LSTM_STEP("v12", NOFILL)
        LSTM_STEP("v13", NOFILL)
        LSTM_STEP("v14", NOFILL)
        LSTM_STEP("v15", FILLB)
        "v_add_u32 %[vX], 32, %[vX]\n\t"
        "s_add_u32 s20, s20, 1\n\t"
        "s_cmp_lt_u32 s20, 64\n\t"
        "s_cbranch_scc1 1b\n\t"
        "s_waitcnt lgkmcnt(0)\n\t"           // final h write drained
        : [c]"+v"(c), [vX]"+v"(vX)
        : [vB]"v"(vB), [vW]"v"(vW),
          [wih0]"v"(wih0), [bias0]"v"(bias0),
          [wih1]"v"(wih1), [bias1]"v"(bias1),
          [cm1]"v"(cm1), [ca1]"v"(ca1), [k2]"v"(k2),
          [w00]"v"(w0p[0]), [w01]"v"(w0p[1]), [w02]"v"(w0p[2]), [w03]"v"(w0p[3]),
          [w04]"v"(w0p[4]), [w05]"v"(w0p[5]), [w06]"v"(w0p[6]), [w07]"v"(w0p[7]),
          [w10]"v"(w1p[0]), [w11]"v"(w1p[1]), [w12]"v"(w1p[2]), [w13]"v"(w1p[3]),
          [w14]"v"(w1p[4]), [w15]"v"(w1p[5]), [w16]"v"(w1p[6]), [w17]"v"(w1p[7])
        : "v8","v9","v10","v11","v12","v13","v14","v15",
          "v20","v21","v22","v23","v24","v25","v26","v27","v28","v29",
          "v32","v33","v34","v35","v36","v37","v38","v39",
          "v40","v41","v42","v43","v44","v45","v46","v47",
          "s20","scc","memory");
#undef LSTM_STEP
#undef NOFILL
#undef FILLA
#undef FILLB

    // ---- reverse direction: one step on x[:, T-1], zero state; lanes hl<16
    if (hl < 16) {
        const int j = hl;
        const float xl = smem[rbase + 32 + 511];
        const float zi = fmaf(xl, W_ih_r[j],      b_ih_r[j]      + b_hh_r[j]);
        const float zg = fmaf(xl, W_ih_r[32 + j], b_ih_r[32 + j] + b_hh_r[32 + j]);
        const float zo = fmaf(xl, W_ih_r[48 + j], b_ih_r[48 + j] + b_hh_r[48 + j]);
        const float si = __builtin_amdgcn_rcpf(1.0f + __builtin_amdgcn_exp2f(-zi * LOG2E));
        const float tg = fmaf(__builtin_amdgcn_rcpf(1.0f + __builtin_amdgcn_exp2f(-2.0f * zg * LOG2E)), 2.0f, -1.0f);
        const float so = __builtin_amdgcn_rcpf(1.0f + __builtin_amdgcn_exp2f(-zo * LOG2E));
        const float cr = si * tg;
        const float th = fmaf(__builtin_amdgcn_rcpf(1.0f + __builtin_amdgcn_exp2f(-2.0f * cr * LOG2E)), 2.0f, -1.0f);
        smem[rbase + 16 + j] = so * th;
    }
    __syncthreads();

    // ---- MLP head ----
    const int m = hl & 15;
    float hid = b1[m];
#pragma unroll
    for (int n = 0; n < 16; ++n) hid = fmaf(smem[rbase + n],      W1[m * 32 + n],      hid);
#pragma unroll
    for (int n = 0; n < 16; ++n) hid = fmaf(smem[rbase + 16 + n], W1[m * 32 + 16 + n], hid);
    hid = (hid > 0.0f) ? hid : (0.2f * hid);

    float v = hid * W2[m];
    v += __shfl_xor(v, 1);
    v += __shfl_xor(v, 2);
    v += __shfl_xor(v, 4);
    v += __shfl_xor(v, 8);
    if (hl == 0) out[b] = v + b2[0];
}

extern "C" void kernel_launch(void* const* d_in, const int* in_sizes, int n_in,
                              void* d_out, int out_size, void* d_ws, size_t ws_size,
                              hipStream_t stream) {
    const float* x      = (const float*)d_in[0];
    const float* W_ih_f = (const float*)d_in[1];
    const float* W_hh_f = (const float*)d_in[2];
    const float* b_ih_f = (const float*)d_in[3];
    const float* b_hh_f = (const float*)d_in[4];
    const float* W_ih_r = (const float*)d_in[5];
    const float* W_hh_r = (const float*)d_in[6];
    const float* b_ih_r = (const float*)d_in[7];
    const float* b_hh_r = (const float*)d_in[8];
    const float* W1     = (const float*)d_in[9];
    const float* b1     = (const float*)d_in[10];
    const float* W2     = (const float*)d_in[11];
    const float* b2     = (const float*)d_in[12];
    float* out = (float*)d_out;

    const int B = in_sizes[0] / T_LEN;   // 2048
    dim3 grid(B / 8), block(256);
    size_t lds_bytes = 8 * 560 * sizeof(float);   // 17920 B/block
    hipLaunchKernelGGL(bilstm_head_kernel, grid, block, lds_bytes, stream,
                       x, W_ih_f, W_hh_f, b_ih_f, b_hh_f,
                       W_ih_r, W_hh_r, b_ih_r, b_hh_r,
                       W1, b1, W2, b2, out);
}